// Round 12
// baseline (165.896 us; speedup 1.0000x reference)
//
#include <hip/hip_runtime.h>
#include <hip/hip_bf16.h>

// ObjectSelector: fused MLP -> segment softmax -> segment-weighted embedding.
// Algebra: logit_i = x2_i . u_{s_i} + c_{s_i}   (u_s = Wk @ q_s, c_s = bk.q_s, /16 folded in)
//          emb_s   = (sum_i e_i x2_i)/den @ Wv + bv     (linearity of V-projection)
// kA computes GEMM1/GEMM2 TRANSPOSED (x^T = W^T @ obj^T).
// R12 = R11 (128-row tiles, 2048 blocks, 8 waves, nn<8) with launch_bounds
// relaxed (512,4)->(512,3): VGPR cap 128->170. R11's VGPR_Count=64 + 150MB
// WRITE showed the allocator spilled acc[2][8] itself under the 128 cap;
// occupancy is LDS-bound (69KB -> 2 blocks/CU) so the relaxed cap costs
// nothing. Tests the 128-row hypothesis cleanly (halved weight streaming,
// halved per-row phase overhead).

typedef __attribute__((ext_vector_type(8))) short bf16x8;
typedef __attribute__((ext_vector_type(4))) float f32x4;
typedef __attribute__((ext_vector_type(4))) short s16x4;

__device__ __forceinline__ float b2f(short s) {
    unsigned int u = ((unsigned int)(unsigned short)s) << 16;
    float f;
    __builtin_memcpy(&f, &u, 4);
    return f;
}
__device__ __forceinline__ short f2b(float x) {
    __hip_bfloat16 h = __float2bfloat16(x);
    short s;
    __builtin_memcpy(&s, &h, 2);
    return s;
}
__device__ __forceinline__ unsigned pack2(float a, float b) {
    return ((unsigned)(unsigned short)f2b(a)) | (((unsigned)(unsigned short)f2b(b)) << 16);
}
__device__ __forceinline__ f32x4 vmax0(f32x4 v) {
    f32x4 r;
    r[0] = fmaxf(v[0], 0.f); r[1] = fmaxf(v[1], 0.f);
    r[2] = fmaxf(v[2], 0.f); r[3] = fmaxf(v[3], 0.f);
    return r;
}

#define MFMA16(a, b, c) __builtin_amdgcn_mfma_f32_16x16x32_bf16(a, b, c, 0, 0, 0)
#define SWZ(row) (((row) & 7) << 4)   // XOR-swizzle on 16B chunks (G4 bank-conflict fix)

// ---------------------------------------------------------------------------
// prep0: weights -> bf16.
//  W0f: frag-ordered W0^T: i = ((wh*4+ks)*64+lane)*8+e,  wh in [0,16)
//       value = W0[k][h], h=wh*16+(lane&15), k=ks*32+(lane>>4)*8+e
//  W1f: frag-ordered W1^T: i = ((wh*8+ks)*64+lane)*8+e  (same mapping, K=256)
//  Wqt[n][k] (256x256), Wkvb straight copy (256x512)   (for kPrep1)
// ---------------------------------------------------------------------------
__global__ void kPrep0(const float* __restrict__ W0, const float* __restrict__ W1,
                       const float* __restrict__ Wkv, const float* __restrict__ Wq,
                       short* __restrict__ W0f, short* __restrict__ W1f,
                       short* __restrict__ Wkvb, short* __restrict__ Wqt) {
    int i = blockIdx.x * 256 + threadIdx.x;  // grid covers 131072
    if (i < 32768) {
        int e = i & 7, lane = (i >> 3) & 63, ks = (i >> 9) & 3, wh = (i >> 11) & 15;
        int h = wh * 16 + (lane & 15);
        int k = ks * 32 + (lane >> 4) * 8 + e;
        W0f[i] = f2b(W0[k * 256 + h]);
    }
    if (i < 65536) {
        int e = i & 7, lane = (i >> 3) & 63, ks = (i >> 9) & 7, wh = (i >> 12) & 15;
        int h = wh * 16 + (lane & 15);
        int k = ks * 32 + (lane >> 4) * 8 + e;
        W1f[i] = f2b(W1[k * 256 + h]);
        int n = i >> 8, kk = i & 255;
        Wqt[i] = f2b(Wq[kk * 256 + n]);
    }
    if (i < 131072) Wkvb[i] = f2b(Wkv[i]);
}

// ---------------------------------------------------------------------------
// prep1: per 64 context rows: q = ctx@Wq + bq; c = (q.bk)/16; u = (q@Wk^T)/16
// ---------------------------------------------------------------------------
__global__ __launch_bounds__(256) void kPrep1(
        const float* __restrict__ context, const short* __restrict__ Wqt,
        const float* __restrict__ bq, const short* __restrict__ Wkvb,
        const float* __restrict__ bkv, float* __restrict__ u_ws,
        float* __restrict__ c_ws) {
    __shared__ short cbuf[64 * 256];
    __shared__ float pl[4][64];
    const int t = threadIdx.x, w = t >> 6, l = t & 63;
    const int lo = l & 15, hi = l >> 4;
    const int base = blockIdx.x * 64;

    const float* src = context + (size_t)base * 256;
#pragma unroll
    for (int i = 0; i < 16; ++i) {
        int fi = (t + i * 256) * 4;
        float4 v = *(const float4*)(src + fi);
        int row = fi >> 8, col = fi & 255;
        int byte = (row << 9) + (col << 1);
        byte ^= SWZ(row);
        s16x4 pk;
        pk[0] = f2b(v.x); pk[1] = f2b(v.y); pk[2] = f2b(v.z); pk[3] = f2b(v.w);
        *(s16x4*)((char*)cbuf + byte) = pk;
    }
    __syncthreads();

    f32x4 acc[4][4] = {};
    const short* wqb = Wqt + (size_t)(w * 64 + lo) * 256 + hi * 8;
#pragma unroll
    for (int ks = 0; ks < 8; ++ks) {
        bf16x8 a[4], b[4];
#pragma unroll
        for (int m = 0; m < 4; ++m) {
            int row = m * 16 + lo;
            int byte = (row << 9) + ks * 64 + hi * 16;
            byte ^= SWZ(row);
            a[m] = *(const bf16x8*)((const char*)cbuf + byte);
        }
#pragma unroll
        for (int n = 0; n < 4; ++n) b[n] = *(const bf16x8*)(wqb + n * 16 * 256 + ks * 32);
#pragma unroll
        for (int m = 0; m < 4; ++m)
#pragma unroll
            for (int n = 0; n < 4; ++n) acc[m][n] = MFMA16(a[m], b[n], acc[m][n]);
    }
    __syncthreads();

    float bqv[4];
#pragma unroll
    for (int n = 0; n < 4; ++n) bqv[n] = bq[w * 64 + n * 16 + lo];
#pragma unroll
    for (int m = 0; m < 4; ++m)
#pragma unroll
        for (int n = 0; n < 4; ++n)
#pragma unroll
            for (int j = 0; j < 4; ++j) {
                float q = acc[m][n][j] + bqv[n];
                int row = m * 16 + hi * 4 + j;
                int col = w * 64 + n * 16 + lo;
                int byte = (row << 9) + (col << 1);
                byte ^= SWZ(row);
                *(short*)((char*)cbuf + byte) = f2b(q);
            }
    __syncthreads();

    {
        float p = 0.f;
#pragma unroll
        for (int j = 0; j < 8; ++j) {
            int col = w * 64 + j * 8;
            int byte = (l << 9) + (col << 1);
            byte ^= SWZ(l);
            bf16x8 xv = *(const bf16x8*)((const char*)cbuf + byte);
            const float* bp = bkv + col;
            p += b2f(xv[0]) * bp[0] + b2f(xv[1]) * bp[1] + b2f(xv[2]) * bp[2] + b2f(xv[3]) * bp[3]
               + b2f(xv[4]) * bp[4] + b2f(xv[5]) * bp[5] + b2f(xv[6]) * bp[6] + b2f(xv[7]) * bp[7];
        }
        pl[w][l] = p;
    }
    __syncthreads();
    if (t < 64) c_ws[base + t] = (pl[0][t] + pl[1][t] + pl[2][t] + pl[3][t]) * 0.0625f;

#pragma unroll
    for (int m = 0; m < 4; ++m)
#pragma unroll
        for (int n = 0; n < 4; ++n) acc[m][n] = (f32x4){0.f, 0.f, 0.f, 0.f};
    const short* wkb = Wkvb + (size_t)(w * 64 + lo) * 512 + hi * 8;
#pragma unroll
    for (int ks = 0; ks < 8; ++ks) {
        bf16x8 a[4], b[4];
#pragma unroll
        for (int m = 0; m < 4; ++m) {
            int row = m * 16 + lo;
            int byte = (row << 9) + ks * 64 + hi * 16;
            byte ^= SWZ(row);
            a[m] = *(const bf16x8*)((const char*)cbuf + byte);
        }
#pragma unroll
        for (int n = 0; n < 4; ++n) b[n] = *(const bf16x8*)(wkb + n * 16 * 512 + ks * 32);
#pragma unroll
        for (int m = 0; m < 4; ++m)
#pragma unroll
            for (int n = 0; n < 4; ++n) acc[m][n] = MFMA16(a[m], b[n], acc[m][n]);
    }
#pragma unroll
    for (int m = 0; m < 4; ++m)
#pragma unroll
        for (int n = 0; n < 4; ++n)
#pragma unroll
            for (int j = 0; j < 4; ++j) {
                int s = base + m * 16 + hi * 4 + j;
                int col = w * 64 + n * 16 + lo;
                u_ws[(size_t)s * 256 + col] = acc[m][n][j] * 0.0625f;
            }
}

// ---------------------------------------------------------------------------
// kernel A (128-row tile, 8-wave, transposed-MFMA): per 128 objects, 512 thr.
//  wave w covers h-blocks wh = w*2+mh; acc[mh][nn]: lane holds x for
//  m = nn*16+(l&15) (nn<8 -> 128 rows), h = wh*16+(l>>4)*4+j.
// LDS overlay (69KB -> 2 blocks/CU):
//   x1b = smem[0,64K)       x1 bf16 [128][256]
//   bufIn = smem+32K        objects bf16 [128][128] on x1 rows 64..127
//   x2b = smem[0,64K)       x2, written after barrier 3
// 5 barriers. XCD-chunked swizzle; vector epilogues; unrolled flush-reduce.
// ---------------------------------------------------------------------------
__global__ __launch_bounds__(512, 3) void kA(
        const float* __restrict__ objects, const int* __restrict__ segids,
        const short* __restrict__ W0f, const short* __restrict__ W1f,
        const float* __restrict__ b0, const float* __restrict__ b1,
        const float* __restrict__ u_ws, const float* __restrict__ c_ws,
        float* __restrict__ e_ws, float* __restrict__ Y, float* __restrict__ D) {
    __shared__ char smem[65536];
    __shared__ float pl[8][128];
    __shared__ float e_sh[128];
    __shared__ int sid_sh[128];
    char* x1b   = smem;           // x1 bf16 [128][256]
    char* bufIn = smem + 32768;   // objects bf16 [128][128], overlays x1 rows 64..127
    char* x2b   = smem;           // x2 bf16 [128][256], written after barrier 3

    const int t = threadIdx.x, w = t >> 6, l = t & 63;
    const int lo = l & 15, hi = l >> 4;
    // T1: XCD-chunked swizzle (2048 % 8 == 0)
    const int bid = (blockIdx.x & 7) * (gridDim.x >> 3) + (blockIdx.x >> 3);
    const size_t base_row = (size_t)bid * 128;

    if (t < 128) sid_sh[t] = segids[base_row + t];

    // stage objects 128x128 fp32 -> bf16 swizzled (512 threads: 8 iters)
    const float* src = objects + base_row * 128;
#pragma unroll
    for (int i = 0; i < 8; ++i) {
        int fi = (t + i * 512) * 4;
        float4 v = *(const float4*)(src + fi);
        int row = fi >> 7, col = fi & 127;
        int byte = (row << 8) + (col << 1);
        byte ^= SWZ(row);
        uint2 pk;
        pk.x = pack2(v.x, v.y);
        pk.y = pack2(v.z, v.w);
        *(uint2*)(bufIn + byte) = pk;
    }
    __syncthreads();  // barrier 1: bufIn ready

    // GEMM1 (transposed): x1^T = W0^T @ obj^T.  A = W0f frags, B = bufIn rows.
    f32x4 acc[2][8] = {};
#pragma unroll
    for (int ks = 0; ks < 4; ++ks) {
        bf16x8 av[2], bv[8];
#pragma unroll
        for (int mh = 0; mh < 2; ++mh)
            av[mh] = *(const bf16x8*)(W0f + ((((w * 2 + mh) * 4 + ks) << 9) + (l << 3)));
#pragma unroll
        for (int nn = 0; nn < 8; ++nn) {
            int m = nn * 16 + lo;
            int byte = (m << 8) + (ks << 6) + (hi << 4);
            byte ^= SWZ(m);
            bv[nn] = *(const bf16x8*)(bufIn + byte);
        }
        __builtin_amdgcn_s_setprio(1);
#pragma unroll
        for (int mh = 0; mh < 2; ++mh)
#pragma unroll
            for (int nn = 0; nn < 8; ++nn) acc[mh][nn] = MFMA16(av[mh], bv[nn], acc[mh][nn]);
        __builtin_amdgcn_s_setprio(0);
    }
    __syncthreads();  // barrier 1b: bufIn reads done before x1 rows 64..127 written

    // epilogue 1: x1[m][h] = relu(x + b0) — vector ops, b64 stores
#pragma unroll
    for (int mh = 0; mh < 2; ++mh) {
        const int hcol = (w * 2 + mh) * 16 + hi * 4;
        f32x4 bb = *(const f32x4*)(b0 + hcol);
#pragma unroll
        for (int nn = 0; nn < 8; ++nn) {
            f32x4 v = vmax0(acc[mh][nn] + bb);
            int m = nn * 16 + lo;
            int byte = (m << 9) + (hcol << 1);
            byte ^= SWZ(m);
            uint2 pk;
            pk.x = pack2(v[0], v[1]);
            pk.y = pack2(v[2], v[3]);
            *(uint2*)(x1b + byte) = pk;
        }
    }
    __syncthreads();  // barrier 2: x1 ready

    // GEMM2 (transposed): x2^T = W1^T @ x1^T.  A = W1f frags, B = x1 rows (b128).
#pragma unroll
    for (int mh = 0; mh < 2; ++mh)
#pragma unroll
        for (int nn = 0; nn < 8; ++nn) acc[mh][nn] = (f32x4){0.f, 0.f, 0.f, 0.f};
#pragma unroll
    for (int ks = 0; ks < 8; ++ks) {
        bf16x8 av[2], bv[8];
#pragma unroll
        for (int mh = 0; mh < 2; ++mh)
            av[mh] = *(const bf16x8*)(W1f + ((((w * 2 + mh) * 8 + ks) << 9) + (l << 3)));
#pragma unroll
        for (int nn = 0; nn < 8; ++nn) {
            int m = nn * 16 + lo;
            int byte = (m << 9) + (ks << 6) + (hi << 4);
            byte ^= SWZ(m);
            bv[nn] = *(const bf16x8*)(x1b + byte);
        }
        __builtin_amdgcn_s_setprio(1);
#pragma unroll
        for (int mh = 0; mh < 2; ++mh)
#pragma unroll
            for (int nn = 0; nn < 8; ++nn) acc[mh][nn] = MFMA16(av[mh], bv[nn], acc[mh][nn]);
        __builtin_amdgcn_s_setprio(0);
    }

    // epilogue 2: bias+relu in acc (vector), fused logit partials (scalar p[8])
    int sids[8];
#pragma unroll
    for (int nn = 0; nn < 8; ++nn) sids[nn] = sid_sh[nn * 16 + lo];
    float p[8] = {};
#pragma unroll
    for (int mh = 0; mh < 2; ++mh) {
        const int hcol = (w * 2 + mh) * 16 + hi * 4;
        f32x4 bb = *(const f32x4*)(b1 + hcol);
#pragma unroll
        for (int nn = 0; nn < 8; ++nn) {
            f32x4 u4 = *(const f32x4*)(u_ws + (size_t)sids[nn] * 256 + hcol);
            f32x4 v = vmax0(acc[mh][nn] + bb);
            acc[mh][nn] = v;
            p[nn] += v[0] * u4[0] + v[1] * u4[1] + v[2] * u4[2] + v[3] * u4[3];
        }
    }
    // cross-hi reduce of logit partials (lanes l, l^16, l^32, l^48)
#pragma unroll
    for (int nn = 0; nn < 8; ++nn) {
        float pv = p[nn];
        pv += __shfl_xor(pv, 16);
        pv += __shfl_xor(pv, 32);
        if (hi == 0) pl[w][nn * 16 + lo] = pv;
    }
    __syncthreads();  // barrier 3: x1/bufIn dead; pl published

    // waves 0-1 compute e and publish to e_sh (ready at barrier 4)
    if (t < 128) {
        float logit = ((pl[0][t] + pl[1][t]) + (pl[2][t] + pl[3][t]))
                    + ((pl[4][t] + pl[5][t]) + (pl[6][t] + pl[7][t])) + c_ws[sid_sh[t]];
        float e = __expf(logit);  // logits tiny: no max-subtraction needed
        e_sh[t] = e;
        e_ws[base_row + t] = e;
    }

    // store x2 (overlays x1)
#pragma unroll
    for (int mh = 0; mh < 2; ++mh) {
        const int hcol = (w * 2 + mh) * 16 + hi * 4;
#pragma unroll
        for (int nn = 0; nn < 8; ++nn) {
            int m = nn * 16 + lo;
            int byte = (m << 9) + (hcol << 1);
            byte ^= SWZ(m);
            uint2 pk;
            pk.x = pack2(acc[mh][nn][0], acc[mh][nn][1]);
            pk.y = pack2(acc[mh][nn][2], acc[mh][nn][3]);
            *(uint2*)(x2b + byte) = pk;
        }
    }
    __syncthreads();  // barrier 4: x2 + e_sh ready

    // Y/D reduce: row-split across thread halves (col = t&255, rows half*64..+63);
    // statically unrolled; flush at run boundaries or half-end (partial sums
    // merge via atomics). || short-circuit guards sid_sh[128] OOB.
    {
        const int col = t & 255;
        const int hbase = (t >> 8) * 64;
        const int hend = hbase + 63;
        float ysum = 0.f, dsum = 0.f;
#pragma unroll
        for (int rr = 0; rr < 64; ++rr) {
            const int r = hbase + rr;
            float er = e_sh[r];
            int byte = ((r << 9) + (col << 1)) ^ SWZ(r);
            ysum += er * b2f(*(const short*)(x2b + byte));
            dsum += er;
            if ((r == hend) || (sid_sh[r + 1] != sid_sh[r])) {  // uniform flush
                int s = sid_sh[r];
                atomicAdd(Y + (size_t)s * 256 + col, ysum);
                if (col == 0) atomicAdd(D + s, dsum);
                ysum = 0.f;
                dsum = 0.f;
            }
        }
    }
}

// ---------------------------------------------------------------------------
// kEmbW: 8 segments/block: emb_s = (Y_s/den) @ Wv + (den/max(den,eps))*bv
//        + fused w_i = e_i / max(D[sid_i], eps) (grid-stride tail)
// ---------------------------------------------------------------------------
__global__ __launch_bounds__(256) void kEmbW(const float* __restrict__ Y,
                                             const float* __restrict__ D,
                                             const float* __restrict__ Wkv,
                                             const float* __restrict__ bkv,
                                             const float* __restrict__ e,
                                             const int* __restrict__ segids,
                                             float* __restrict__ emb,
                                             float* __restrict__ wout, int nobj) {
    __shared__ float ysh[8][256];
    __shared__ float sw[8];
    const int t = threadIdx.x;
    const int s0 = blockIdx.x * 8;
#pragma unroll
    for (int i = 0; i < 8; ++i) {
        float d = D[s0 + i];
        float dm = fmaxf(d, 1e-9f);
        ysh[i][t] = Y[(size_t)(s0 + i) * 256 + t] / dm;
        if (t == 0) sw[i] = d / dm;
    }
    __syncthreads();
    float acc[8] = {0.f, 0.f, 0.f, 0.f, 0.f, 0.f, 0.f, 0.f};
    for (int h = 0; h < 256; ++h) {
        float wv = Wkv[(size_t)h * 512 + 256 + t];  // fp32 V weights (accuracy)
#pragma unroll
        for (int i = 0; i < 8; ++i) acc[i] += ysh[i][h] * wv;
    }
    float bv = bkv[256 + t];
#pragma unroll
    for (int i = 0; i < 8; ++i) emb[(size_t)(s0 + i) * 256 + t] = acc[i] + sw[i] * bv;

    // fused w output
    for (int i = blockIdx.x * 256 + t; i < nobj; i += gridDim.x * 256)
        wout[i] = e[i] / fmaxf(D[segids[i]], 1e-9f);
}

// ---------------------------------------------------------------------------
extern "C" void kernel_launch(void* const* d_in, const int* in_sizes, int n_in,
                              void* d_out, int out_size, void* d_ws, size_t ws_size,
                              hipStream_t stream) {
    const float* objects = (const float*)d_in[0];
    const float* context = (const float*)d_in[1];
    const int* segids    = (const int*)d_in[2];
    const float* W0  = (const float*)d_in[4];
    const float* b0  = (const float*)d_in[5];
    const float* W1  = (const float*)d_in[6];
    const float* b1  = (const float*)d_in[7];
    const float* Wkv = (const float*)d_in[8];
    const float* bkv = (const float*)d_in[9];
    const float* Wq  = (const float*)d_in[10];
    const float* bq  = (const float*)d_in[11];

    const int NT = in_sizes[2];        // 262144
    const int B  = in_sizes[1] / 256;  // 4096

    char* wsb = (char*)d_ws;
    short* W0f  = (short*)(wsb + 0);        // 64 KB
    short* W1f  = (short*)(wsb + 65536);    // 128 KB
    short* Wkvb = (short*)(wsb + 196608);   // 256 KB
    short* Wqt  = (short*)(wsb + 458752);   // 128 KB
    float* u_ws = (float*)(wsb + 589824);   // 4 MB
    float* c_ws = (float*)(wsb + 4784128);  // 16 KB
    float* e_ws = (float*)(wsb + 4800512);  // 1 MB
    float* Y    = (float*)(wsb + 5849088);  // 4 MB
    float* D    = (float*)(wsb + 10043392); // 16 KB

    float* emb_out = (float*)d_out;
    float* w_out   = (float*)d_out + (size_t)B * 256;

    hipMemsetAsync(wsb + 5849088, 0, 4194304 + 16384, stream);  // zero Y, D
    kPrep0<<<512, 256, 0, stream>>>(W0, W1, Wkv, Wq, W0f, W1f, Wkvb, Wqt);
    kPrep1<<<B / 64, 256, 0, stream>>>(context, Wqt, bq, Wkvb, bkv, u_ws, c_ws);
    kA<<<NT / 128, 512, 0, stream>>>(objects, segids, W0f, W1f, b0, b1, u_ws, c_ws, e_ws, Y, D);
    kEmbW<<<B / 8, 256, 0, stream>>>(Y, D, Wkv, bkv, e_ws, segids, emb_out, w_out, NT);
}

// Round 13
// 146.647 us; speedup vs baseline: 1.1313x; 1.1313x over previous
//
#include <hip/hip_runtime.h>
#include <hip/hip_bf16.h>

// ObjectSelector: fused MLP -> segment softmax -> segment-weighted embedding.
// Algebra: logit_i = x2_i . u_{s_i} + c_{s_i}   (u_s = Wk @ q_s, c_s = bk.q_s, /16 folded in)
//          emb_s   = (sum_i e_i x2_i)/den @ Wv + bv     (linearity of V-projection)
// kA computes GEMM1/GEMM2 TRANSPOSED (x^T = W^T @ obj^T).
// R13 = R10 kA (verified best, 64-row tiles, 8 waves, 51.7KB LDS) +
//  (a) flat half-hoist of GEMM2 W1f frags ks=0..3 before barrier 1 (R4-style;
//      L2 latency hides under staging+GEMM1), launch_bounds relaxed to (512,3)
//      so the +32 VGPR can't trigger the R11 spill;
//  (b) kEmbW at 16 seg/block (256 blocks) halving Wv re-streaming.
// R5 lesson: don't add resident tiles. R7/R11 lesson: watch WRITE_SIZE for spill.

typedef __attribute__((ext_vector_type(8))) short bf16x8;
typedef __attribute__((ext_vector_type(4))) float f32x4;
typedef __attribute__((ext_vector_type(4))) short s16x4;

__device__ __forceinline__ float b2f(short s) {
    unsigned int u = ((unsigned int)(unsigned short)s) << 16;
    float f;
    __builtin_memcpy(&f, &u, 4);
    return f;
}
__device__ __forceinline__ short f2b(float x) {
    __hip_bfloat16 h = __float2bfloat16(x);
    short s;
    __builtin_memcpy(&s, &h, 2);
    return s;
}
__device__ __forceinline__ unsigned pack2(float a, float b) {
    return ((unsigned)(unsigned short)f2b(a)) | (((unsigned)(unsigned short)f2b(b)) << 16);
}
__device__ __forceinline__ f32x4 vmax0(f32x4 v) {
    f32x4 r;
    r[0] = fmaxf(v[0], 0.f); r[1] = fmaxf(v[1], 0.f);
    r[2] = fmaxf(v[2], 0.f); r[3] = fmaxf(v[3], 0.f);
    return r;
}

#define MFMA16(a, b, c) __builtin_amdgcn_mfma_f32_16x16x32_bf16(a, b, c, 0, 0, 0)
#define SWZ(row) (((row) & 7) << 4)   // XOR-swizzle on 16B chunks (G4 bank-conflict fix)

// ---------------------------------------------------------------------------
// prep0: weights -> bf16.
//  W0f: frag-ordered W0^T: i = ((wh*4+ks)*64+lane)*8+e,  wh in [0,16)
//       value = W0[k][h], h=wh*16+(lane&15), k=ks*32+(lane>>4)*8+e
//  W1f: frag-ordered W1^T: i = ((wh*8+ks)*64+lane)*8+e  (same mapping, K=256)
//  Wqt[n][k] (256x256), Wkvb straight copy (256x512)   (for kPrep1)
// ---------------------------------------------------------------------------
__global__ void kPrep0(const float* __restrict__ W0, const float* __restrict__ W1,
                       const float* __restrict__ Wkv, const float* __restrict__ Wq,
                       short* __restrict__ W0f, short* __restrict__ W1f,
                       short* __restrict__ Wkvb, short* __restrict__ Wqt) {
    int i = blockIdx.x * 256 + threadIdx.x;  // grid covers 131072
    if (i < 32768) {
        int e = i & 7, lane = (i >> 3) & 63, ks = (i >> 9) & 3, wh = (i >> 11) & 15;
        int h = wh * 16 + (lane & 15);
        int k = ks * 32 + (lane >> 4) * 8 + e;
        W0f[i] = f2b(W0[k * 256 + h]);
    }
    if (i < 65536) {
        int e = i & 7, lane = (i >> 3) & 63, ks = (i >> 9) & 7, wh = (i >> 12) & 15;
        int h = wh * 16 + (lane & 15);
        int k = ks * 32 + (lane >> 4) * 8 + e;
        W1f[i] = f2b(W1[k * 256 + h]);
        int n = i >> 8, kk = i & 255;
        Wqt[i] = f2b(Wq[kk * 256 + n]);
    }
    if (i < 131072) Wkvb[i] = f2b(Wkv[i]);
}

// ---------------------------------------------------------------------------
// prep1: per 64 context rows: q = ctx@Wq + bq; c = (q.bk)/16; u = (q@Wk^T)/16
// ---------------------------------------------------------------------------
__global__ __launch_bounds__(256) void kPrep1(
        const float* __restrict__ context, const short* __restrict__ Wqt,
        const float* __restrict__ bq, const short* __restrict__ Wkvb,
        const float* __restrict__ bkv, float* __restrict__ u_ws,
        float* __restrict__ c_ws) {
    __shared__ short cbuf[64 * 256];
    __shared__ float pl[4][64];
    const int t = threadIdx.x, w = t >> 6, l = t & 63;
    const int lo = l & 15, hi = l >> 4;
    const int base = blockIdx.x * 64;

    const float* src = context + (size_t)base * 256;
#pragma unroll
    for (int i = 0; i < 16; ++i) {
        int fi = (t + i * 256) * 4;
        float4 v = *(const float4*)(src + fi);
        int row = fi >> 8, col = fi & 255;
        int byte = (row << 9) + (col << 1);
        byte ^= SWZ(row);
        s16x4 pk;
        pk[0] = f2b(v.x); pk[1] = f2b(v.y); pk[2] = f2b(v.z); pk[3] = f2b(v.w);
        *(s16x4*)((char*)cbuf + byte) = pk;
    }
    __syncthreads();

    f32x4 acc[4][4] = {};
    const short* wqb = Wqt + (size_t)(w * 64 + lo) * 256 + hi * 8;
#pragma unroll
    for (int ks = 0; ks < 8; ++ks) {
        bf16x8 a[4], b[4];
#pragma unroll
        for (int m = 0; m < 4; ++m) {
            int row = m * 16 + lo;
            int byte = (row << 9) + ks * 64 + hi * 16;
            byte ^= SWZ(row);
            a[m] = *(const bf16x8*)((const char*)cbuf + byte);
        }
#pragma unroll
        for (int n = 0; n < 4; ++n) b[n] = *(const bf16x8*)(wqb + n * 16 * 256 + ks * 32);
#pragma unroll
        for (int m = 0; m < 4; ++m)
#pragma unroll
            for (int n = 0; n < 4; ++n) acc[m][n] = MFMA16(a[m], b[n], acc[m][n]);
    }
    __syncthreads();

    float bqv[4];
#pragma unroll
    for (int n = 0; n < 4; ++n) bqv[n] = bq[w * 64 + n * 16 + lo];
#pragma unroll
    for (int m = 0; m < 4; ++m)
#pragma unroll
        for (int n = 0; n < 4; ++n)
#pragma unroll
            for (int j = 0; j < 4; ++j) {
                float q = acc[m][n][j] + bqv[n];
                int row = m * 16 + hi * 4 + j;
                int col = w * 64 + n * 16 + lo;
                int byte = (row << 9) + (col << 1);
                byte ^= SWZ(row);
                *(short*)((char*)cbuf + byte) = f2b(q);
            }
    __syncthreads();

    {
        float p = 0.f;
#pragma unroll
        for (int j = 0; j < 8; ++j) {
            int col = w * 64 + j * 8;
            int byte = (l << 9) + (col << 1);
            byte ^= SWZ(l);
            bf16x8 xv = *(const bf16x8*)((const char*)cbuf + byte);
            const float* bp = bkv + col;
            p += b2f(xv[0]) * bp[0] + b2f(xv[1]) * bp[1] + b2f(xv[2]) * bp[2] + b2f(xv[3]) * bp[3]
               + b2f(xv[4]) * bp[4] + b2f(xv[5]) * bp[5] + b2f(xv[6]) * bp[6] + b2f(xv[7]) * bp[7];
        }
        pl[w][l] = p;
    }
    __syncthreads();
    if (t < 64) c_ws[base + t] = (pl[0][t] + pl[1][t] + pl[2][t] + pl[3][t]) * 0.0625f;

#pragma unroll
    for (int m = 0; m < 4; ++m)
#pragma unroll
        for (int n = 0; n < 4; ++n) acc[m][n] = (f32x4){0.f, 0.f, 0.f, 0.f};
    const short* wkb = Wkvb + (size_t)(w * 64 + lo) * 512 + hi * 8;
#pragma unroll
    for (int ks = 0; ks < 8; ++ks) {
        bf16x8 a[4], b[4];
#pragma unroll
        for (int m = 0; m < 4; ++m) {
            int row = m * 16 + lo;
            int byte = (row << 9) + ks * 64 + hi * 16;
            byte ^= SWZ(row);
            a[m] = *(const bf16x8*)((const char*)cbuf + byte);
        }
#pragma unroll
        for (int n = 0; n < 4; ++n) b[n] = *(const bf16x8*)(wkb + n * 16 * 512 + ks * 32);
#pragma unroll
        for (int m = 0; m < 4; ++m)
#pragma unroll
            for (int n = 0; n < 4; ++n) acc[m][n] = MFMA16(a[m], b[n], acc[m][n]);
    }
#pragma unroll
    for (int m = 0; m < 4; ++m)
#pragma unroll
        for (int n = 0; n < 4; ++n)
#pragma unroll
            for (int j = 0; j < 4; ++j) {
                int s = base + m * 16 + hi * 4 + j;
                int col = w * 64 + n * 16 + lo;
                u_ws[(size_t)s * 256 + col] = acc[m][n][j] * 0.0625f;
            }
}

// ---------------------------------------------------------------------------
// kernel A (8-wave, transposed-MFMA): per 64 objects, 512 threads.
//  wave w covers h-blocks wh = w*2+mh; acc[mh][nn]: lane holds x for
//  m = nn*16+(l&15), h = wh*16+(l>>4)*4+j.
// LDS: bufIn 16K [0,16K) | x1 32K [16K,48K) | x2 32K [0,32K) after barrier 3.
// 4 barriers. XCD-chunked tile swizzle; vector epilogues; row-split reduce;
// W0f full hoist + W1f half hoist (ks 0..3) before barrier 1.
// ---------------------------------------------------------------------------
__global__ __launch_bounds__(512, 3) void kA(
        const float* __restrict__ objects, const int* __restrict__ segids,
        const short* __restrict__ W0f, const short* __restrict__ W1f,
        const float* __restrict__ b0, const float* __restrict__ b1,
        const float* __restrict__ u_ws, const float* __restrict__ c_ws,
        float* __restrict__ e_ws, float* __restrict__ Y, float* __restrict__ D) {
    __shared__ char smem[49152];
    __shared__ float pl[8][64];
    __shared__ float e_sh[64];
    __shared__ int sid_sh[64];
    char* bufIn = smem;           // objects bf16 [64][128], dead after GEMM1
    char* x1b   = smem + 16384;   // x1 bf16 [64][256], dead after GEMM2
    char* x2b   = smem;           // x2 bf16 [64][256], written after barrier 3

    const int t = threadIdx.x, w = t >> 6, l = t & 63;
    const int lo = l & 15, hi = l >> 4;
    // T1: XCD-chunked swizzle — each XCD gets a contiguous tile chunk (4096%8==0)
    const int bid = (blockIdx.x & 7) * (gridDim.x >> 3) + (blockIdx.x >> 3);
    const size_t base_row = (size_t)bid * 64;

    if (t < 64) sid_sh[t] = segids[base_row + t];

    // hoist GEMM1 weight A-frags + GEMM2 first-half frags: their L2 latency
    // overlaps the HBM staging + GEMM1 below (flat hoist — the R4 pattern).
    bf16x8 w0frag[2][4];  // [mh][ks]
#pragma unroll
    for (int mh = 0; mh < 2; ++mh)
#pragma unroll
        for (int ks = 0; ks < 4; ++ks)
            w0frag[mh][ks] = *(const bf16x8*)(W0f + ((((w * 2 + mh) * 4 + ks) << 9) + (l << 3)));
    bf16x8 w1h[4][2];  // [ks][mh], ks = 0..3
#pragma unroll
    for (int ks = 0; ks < 4; ++ks)
#pragma unroll
        for (int mh = 0; mh < 2; ++mh)
            w1h[ks][mh] = *(const bf16x8*)(W1f + ((((w * 2 + mh) * 8 + ks) << 9) + (l << 3)));

    // stage objects 64x128 fp32 -> bf16 swizzled (512 threads: 4 iters)
    const float* src = objects + base_row * 128;
#pragma unroll
    for (int i = 0; i < 4; ++i) {
        int fi = (t + i * 512) * 4;
        float4 v = *(const float4*)(src + fi);
        int row = fi >> 7, col = fi & 127;
        int byte = (row << 8) + (col << 1);
        byte ^= SWZ(row);
        uint2 pk;
        pk.x = pack2(v.x, v.y);
        pk.y = pack2(v.z, v.w);
        *(uint2*)(bufIn + byte) = pk;
    }
    __syncthreads();  // barrier 1: bufIn ready

    // GEMM1 (transposed): x1^T = W0^T @ obj^T.  A = hoisted frags, B = bufIn rows.
    f32x4 acc[2][4] = {};
#pragma unroll
    for (int ks = 0; ks < 4; ++ks) {
        bf16x8 bv[4];
#pragma unroll
        for (int nn = 0; nn < 4; ++nn) {
            int m = nn * 16 + lo;
            int byte = (m << 8) + (ks << 6) + (hi << 4);
            byte ^= SWZ(m);
            bv[nn] = *(const bf16x8*)(bufIn + byte);
        }
        __builtin_amdgcn_s_setprio(1);
#pragma unroll
        for (int mh = 0; mh < 2; ++mh)
#pragma unroll
            for (int nn = 0; nn < 4; ++nn) acc[mh][nn] = MFMA16(w0frag[mh][ks], bv[nn], acc[mh][nn]);
        __builtin_amdgcn_s_setprio(0);
    }

    // epilogue 1: x1[m][h] = relu(x + b0) — vector ops, b64 stores
#pragma unroll
    for (int mh = 0; mh < 2; ++mh) {
        const int hcol = (w * 2 + mh) * 16 + hi * 4;
        f32x4 bb = *(const f32x4*)(b0 + hcol);
#pragma unroll
        for (int nn = 0; nn < 4; ++nn) {
            f32x4 v = vmax0(acc[mh][nn] + bb);
            int m = nn * 16 + lo;
            int byte = (m << 9) + (hcol << 1);
            byte ^= SWZ(m);
            uint2 pk;
            pk.x = pack2(v[0], v[1]);
            pk.y = pack2(v[2], v[3]);
            *(uint2*)(x1b + byte) = pk;
        }
    }
    __syncthreads();  // barrier 2: x1 ready

    // GEMM2 (transposed): x2^T = W1^T @ x1^T.  A = hoisted (ks<4) + inline frags.
#pragma unroll
    for (int mh = 0; mh < 2; ++mh)
#pragma unroll
        for (int nn = 0; nn < 4; ++nn) acc[mh][nn] = (f32x4){0.f, 0.f, 0.f, 0.f};
#pragma unroll
    for (int ks = 0; ks < 8; ++ks) {
        bf16x8 av[2], bv[4];
        if (ks < 4) {
#pragma unroll
            for (int mh = 0; mh < 2; ++mh) av[mh] = w1h[ks][mh];
        } else {
#pragma unroll
            for (int mh = 0; mh < 2; ++mh)
                av[mh] = *(const bf16x8*)(W1f + ((((w * 2 + mh) * 8 + ks) << 9) + (l << 3)));
        }
#pragma unroll
        for (int nn = 0; nn < 4; ++nn) {
            int m = nn * 16 + lo;
            int byte = (m << 9) + (ks << 6) + (hi << 4);
            byte ^= SWZ(m);
            bv[nn] = *(const bf16x8*)(x1b + byte);
        }
        __builtin_amdgcn_s_setprio(1);
#pragma unroll
        for (int mh = 0; mh < 2; ++mh)
#pragma unroll
            for (int nn = 0; nn < 4; ++nn) acc[mh][nn] = MFMA16(av[mh], bv[nn], acc[mh][nn]);
        __builtin_amdgcn_s_setprio(0);
    }

    // epilogue 2: bias+relu in acc (vector), fused logit partials (vector acc)
    int sids[4];
#pragma unroll
    for (int nn = 0; nn < 4; ++nn) sids[nn] = sid_sh[nn * 16 + lo];
    f32x4 pacc[4] = {};
#pragma unroll
    for (int mh = 0; mh < 2; ++mh) {
        const int hcol = (w * 2 + mh) * 16 + hi * 4;
        f32x4 bb = *(const f32x4*)(b1 + hcol);
#pragma unroll
        for (int nn = 0; nn < 4; ++nn) {
            f32x4 u4 = *(const f32x4*)(u_ws + (size_t)sids[nn] * 256 + hcol);
            f32x4 v = vmax0(acc[mh][nn] + bb);
            acc[mh][nn] = v;
            pacc[nn] += v * u4;
        }
    }
    // cross-hi reduce of logit partials (lanes l, l^16, l^32, l^48)
#pragma unroll
    for (int nn = 0; nn < 4; ++nn) {
        float p = (pacc[nn][0] + pacc[nn][1]) + (pacc[nn][2] + pacc[nn][3]);
        p += __shfl_xor(p, 16);
        p += __shfl_xor(p, 32);
        if (hi == 0) pl[w][nn * 16 + lo] = p;
    }
    __syncthreads();  // barrier 3: x1/bufIn dead; pl published

    // wave 0 computes e and publishes to e_sh (ready at barrier 4)
    if (t < 64) {
        float logit = ((pl[0][t] + pl[1][t]) + (pl[2][t] + pl[3][t]))
                    + ((pl[4][t] + pl[5][t]) + (pl[6][t] + pl[7][t])) + c_ws[sid_sh[t]];
        float e = __expf(logit);  // logits tiny: no max-subtraction needed
        e_sh[t] = e;
        e_ws[base_row + t] = e;
    }

    // store x2 (overlays bufIn + x1 low half)
#pragma unroll
    for (int mh = 0; mh < 2; ++mh) {
        const int hcol = (w * 2 + mh) * 16 + hi * 4;
#pragma unroll
        for (int nn = 0; nn < 4; ++nn) {
            int m = nn * 16 + lo;
            int byte = (m << 9) + (hcol << 1);
            byte ^= SWZ(m);
            uint2 pk;
            pk.x = pack2(acc[mh][nn][0], acc[mh][nn][1]);
            pk.y = pack2(acc[mh][nn][2], acc[mh][nn][3]);
            *(uint2*)(x2b + byte) = pk;
        }
    }
    __syncthreads();  // barrier 4: x2 + e_sh ready

    // Y/D reduce: row-split across thread halves (col = t&255, rows half*32..+31);
    // statically unrolled; flush at run boundaries or half-end (partial sums
    // merge via atomics). || short-circuit guards sid_sh[64] OOB.
    {
        const int col = t & 255;
        const int hbase = (t >> 8) * 32;
        const int hend = hbase + 31;
        float ysum = 0.f, dsum = 0.f;
#pragma unroll
        for (int rr = 0; rr < 32; ++rr) {
            const int r = hbase + rr;
            float er = e_sh[r];
            int byte = ((r << 9) + (col << 1)) ^ SWZ(r);
            ysum += er * b2f(*(const short*)(x2b + byte));
            dsum += er;
            if ((r == hend) || (sid_sh[r + 1] != sid_sh[r])) {  // uniform flush
                int s = sid_sh[r];
                atomicAdd(Y + (size_t)s * 256 + col, ysum);
                if (col == 0) atomicAdd(D + s, dsum);
                ysum = 0.f;
                dsum = 0.f;
            }
        }
    }
}

// ---------------------------------------------------------------------------
// kEmbW: 16 segments/block (halved Wv re-streaming vs 8/block):
//   emb_s = (Y_s/den) @ Wv + (den/max(den,eps))*bv
//   + fused w_i = e_i / max(D[sid_i], eps) (grid-stride tail)
// ---------------------------------------------------------------------------
__global__ __launch_bounds__(256) void kEmbW(const float* __restrict__ Y,
                                             const float* __restrict__ D,
                                             const float* __restrict__ Wkv,
                                             const float* __restrict__ bkv,
                                             const float* __restrict__ e,
                                             const int* __restrict__ segids,
                                             float* __restrict__ emb,
                                             float* __restrict__ wout, int nobj) {
    __shared__ float ysh[16][256];
    __shared__ float sw[16];
    const int t = threadIdx.x;
    const int s0 = blockIdx.x * 16;
#pragma unroll
    for (int i = 0; i < 16; ++i) {
        float d = D[s0 + i];
        float dm = fmaxf(d, 1e-9f);
        ysh[i][t] = Y[(size_t)(s0 + i) * 256 + t] / dm;
        if (t == 0) sw[i] = d / dm;
    }
    __syncthreads();
    float acc[16] = {};
    for (int h = 0; h < 256; ++h) {
        float wv = Wkv[(size_t)h * 512 + 256 + t];  // fp32 V weights (accuracy)
#pragma unroll
        for (int i = 0; i < 16; ++i) acc[i] += ysh[i][h] * wv;
    }
    float bv = bkv[256 + t];
#pragma unroll
    for (int i = 0; i < 16; ++i) emb[(size_t)(s0 + i) * 256 + t] = acc[i] + sw[i] * bv;

    // fused w output
    for (int i = blockIdx.x * 256 + t; i < nobj; i += gridDim.x * 256)
        wout[i] = e[i] / fmaxf(D[segids[i]], 1e-9f);
}

// ---------------------------------------------------------------------------
extern "C" void kernel_launch(void* const* d_in, const int* in_sizes, int n_in,
                              void* d_out, int out_size, void* d_ws, size_t ws_size,
                              hipStream_t stream) {
    const float* objects = (const float*)d_in[0];
    const float* context = (const float*)d_in[1];
    const int* segids    = (const int*)d_in[2];
    const float* W0  = (const float*)d_in[4];
    const float* b0  = (const float*)d_in[5];
    const float* W1  = (const float*)d_in[6];
    const float* b1  = (const float*)d_in[7];
    const float* Wkv = (const float*)d_in[8];
    const float* bkv = (const float*)d_in[9];
    const float* Wq  = (const float*)d_in[10];
    const float* bq  = (const float*)d_in[11];

    const int NT = in_sizes[2];        // 262144
    const int B  = in_sizes[1] / 256;  // 4096

    char* wsb = (char*)d_ws;
    short* W0f  = (short*)(wsb + 0);        // 64 KB
    short* W1f  = (short*)(wsb + 65536);    // 128 KB
    short* Wkvb = (short*)(wsb + 196608);   // 256 KB
    short* Wqt  = (short*)(wsb + 458752);   // 128 KB
    float* u_ws = (float*)(wsb + 589824);   // 4 MB
    float* c_ws = (float*)(wsb + 4784128);  // 16 KB
    float* e_ws = (float*)(wsb + 4800512);  // 1 MB
    float* Y    = (float*)(wsb + 5849088);  // 4 MB
    float* D    = (float*)(wsb + 10043392); // 16 KB

    float* emb_out = (float*)d_out;
    float* w_out   = (float*)d_out + (size_t)B * 256;

    hipMemsetAsync(wsb + 5849088, 0, 4194304 + 16384, stream);  // zero Y, D
    kPrep0<<<512, 256, 0, stream>>>(W0, W1, Wkv, Wq, W0f, W1f, Wkvb, Wqt);
    kPrep1<<<B / 64, 256, 0, stream>>>(context, Wqt, bq, Wkvb, bkv, u_ws, c_ws);
    kA<<<NT / 64, 512, 0, stream>>>(objects, segids, W0f, W1f, b0, b1, u_ws, c_ws, e_ws, Y, D);
    kEmbW<<<B / 16, 256, 0, stream>>>(Y, D, Wkv, bkv, e_ws, segids, emb_out, w_out, NT);
}

// Round 14
// 142.407 us; speedup vs baseline: 1.1649x; 1.0298x over previous
//
#include <hip/hip_runtime.h>
#include <hip/hip_bf16.h>

// ObjectSelector: fused MLP -> segment softmax -> segment-weighted embedding.
// Algebra: logit_i = x2_i . u_{s_i} + c_{s_i}   (u_s = Wk @ q_s, c_s = bk.q_s, /16 folded in)
//          emb_s   = (sum_i e_i x2_i)/den @ Wv + bv     (linearity of V-projection)
// kA computes GEMM1/GEMM2 TRANSPOSED (x^T = W^T @ obj^T).
// R14 = R10 kA restored EXACTLY (verified best: 64-row tiles, 8 waves,
// launch_bounds(512,4), VGPR 44, kA ~112us) + Y/D zeroing folded into kPrep0
// (deletes the memset dispatch) + kEmbW 16 seg/block (R13-measured neutral).
// Lessons ledger: R5 don't add resident tiles; R7/R11 spill signature =
// WRITE_SIZE balloon; R9/R13 compiler folds flat reg-hoists; R11/R12 bigger
// tiles lose to occupancy.

typedef __attribute__((ext_vector_type(8))) short bf16x8;
typedef __attribute__((ext_vector_type(4))) float f32x4;
typedef __attribute__((ext_vector_type(4))) short s16x4;

__device__ __forceinline__ float b2f(short s) {
    unsigned int u = ((unsigned int)(unsigned short)s) << 16;
    float f;
    __builtin_memcpy(&f, &u, 4);
    return f;
}
__device__ __forceinline__ short f2b(float x) {
    __hip_bfloat16 h = __float2bfloat16(x);
    short s;
    __builtin_memcpy(&s, &h, 2);
    return s;
}
__device__ __forceinline__ unsigned pack2(float a, float b) {
    return ((unsigned)(unsigned short)f2b(a)) | (((unsigned)(unsigned short)f2b(b)) << 16);
}
__device__ __forceinline__ f32x4 vmax0(f32x4 v) {
    f32x4 r;
    r[0] = fmaxf(v[0], 0.f); r[1] = fmaxf(v[1], 0.f);
    r[2] = fmaxf(v[2], 0.f); r[3] = fmaxf(v[3], 0.f);
    return r;
}

#define MFMA16(a, b, c) __builtin_amdgcn_mfma_f32_16x16x32_bf16(a, b, c, 0, 0, 0)
#define SWZ(row) (((row) & 7) << 4)   // XOR-swizzle on 16B chunks (G4 bank-conflict fix)

// ---------------------------------------------------------------------------
// prep0: weights -> bf16 + Y/D zeroing (replaces the memset dispatch).
//  W0f: frag-ordered W0^T: i = ((wh*4+ks)*64+lane)*8+e,  wh in [0,16)
//       value = W0[k][h], h=wh*16+(lane&15), k=ks*32+(lane>>4)*8+e
//  W1f: frag-ordered W1^T: i = ((wh*8+ks)*64+lane)*8+e  (same mapping, K=256)
//  Wqt[n][k] (256x256), Wkvb straight copy (256x512)   (for kPrep1)
// ---------------------------------------------------------------------------
__global__ void kPrep0(const float* __restrict__ W0, const float* __restrict__ W1,
                       const float* __restrict__ Wkv, const float* __restrict__ Wq,
                       short* __restrict__ W0f, short* __restrict__ W1f,
                       short* __restrict__ Wkvb, short* __restrict__ Wqt,
                       float* __restrict__ Y, float* __restrict__ D) {
    int i = blockIdx.x * 256 + threadIdx.x;  // grid covers 131072
    if (i < 32768) {
        int e = i & 7, lane = (i >> 3) & 63, ks = (i >> 9) & 3, wh = (i >> 11) & 15;
        int h = wh * 16 + (lane & 15);
        int k = ks * 32 + (lane >> 4) * 8 + e;
        W0f[i] = f2b(W0[k * 256 + h]);
    }
    if (i < 65536) {
        int e = i & 7, lane = (i >> 3) & 63, ks = (i >> 9) & 7, wh = (i >> 12) & 15;
        int h = wh * 16 + (lane & 15);
        int k = ks * 32 + (lane >> 4) * 8 + e;
        W1f[i] = f2b(W1[k * 256 + h]);
        int n = i >> 8, kk = i & 255;
        Wqt[i] = f2b(Wq[kk * 256 + n]);
    }
    if (i < 131072) Wkvb[i] = f2b(Wkv[i]);

    // Y/D zeroing: 1048576 Y floats / 131072 threads = 8 per thread
    {
        f32x4 z = {0.f, 0.f, 0.f, 0.f};
        float* yp = Y + (size_t)i * 8;
        *(f32x4*)yp = z;
        *(f32x4*)(yp + 4) = z;
        if (i < 4096) D[i] = 0.f;
    }
}

// ---------------------------------------------------------------------------
// prep1: per 64 context rows: q = ctx@Wq + bq; c = (q.bk)/16; u = (q@Wk^T)/16
// ---------------------------------------------------------------------------
__global__ __launch_bounds__(256) void kPrep1(
        const float* __restrict__ context, const short* __restrict__ Wqt,
        const float* __restrict__ bq, const short* __restrict__ Wkvb,
        const float* __restrict__ bkv, float* __restrict__ u_ws,
        float* __restrict__ c_ws) {
    __shared__ short cbuf[64 * 256];
    __shared__ float pl[4][64];
    const int t = threadIdx.x, w = t >> 6, l = t & 63;
    const int lo = l & 15, hi = l >> 4;
    const int base = blockIdx.x * 64;

    const float* src = context + (size_t)base * 256;
#pragma unroll
    for (int i = 0; i < 16; ++i) {
        int fi = (t + i * 256) * 4;
        float4 v = *(const float4*)(src + fi);
        int row = fi >> 8, col = fi & 255;
        int byte = (row << 9) + (col << 1);
        byte ^= SWZ(row);
        s16x4 pk;
        pk[0] = f2b(v.x); pk[1] = f2b(v.y); pk[2] = f2b(v.z); pk[3] = f2b(v.w);
        *(s16x4*)((char*)cbuf + byte) = pk;
    }
    __syncthreads();

    f32x4 acc[4][4] = {};
    const short* wqb = Wqt + (size_t)(w * 64 + lo) * 256 + hi * 8;
#pragma unroll
    for (int ks = 0; ks < 8; ++ks) {
        bf16x8 a[4], b[4];
#pragma unroll
        for (int m = 0; m < 4; ++m) {
            int row = m * 16 + lo;
            int byte = (row << 9) + ks * 64 + hi * 16;
            byte ^= SWZ(row);
            a[m] = *(const bf16x8*)((const char*)cbuf + byte);
        }
#pragma unroll
        for (int n = 0; n < 4; ++n) b[n] = *(const bf16x8*)(wqb + n * 16 * 256 + ks * 32);
#pragma unroll
        for (int m = 0; m < 4; ++m)
#pragma unroll
            for (int n = 0; n < 4; ++n) acc[m][n] = MFMA16(a[m], b[n], acc[m][n]);
    }
    __syncthreads();

    float bqv[4];
#pragma unroll
    for (int n = 0; n < 4; ++n) bqv[n] = bq[w * 64 + n * 16 + lo];
#pragma unroll
    for (int m = 0; m < 4; ++m)
#pragma unroll
        for (int n = 0; n < 4; ++n)
#pragma unroll
            for (int j = 0; j < 4; ++j) {
                float q = acc[m][n][j] + bqv[n];
                int row = m * 16 + hi * 4 + j;
                int col = w * 64 + n * 16 + lo;
                int byte = (row << 9) + (col << 1);
                byte ^= SWZ(row);
                *(short*)((char*)cbuf + byte) = f2b(q);
            }
    __syncthreads();

    {
        float p = 0.f;
#pragma unroll
        for (int j = 0; j < 8; ++j) {
            int col = w * 64 + j * 8;
            int byte = (l << 9) + (col << 1);
            byte ^= SWZ(l);
            bf16x8 xv = *(const bf16x8*)((const char*)cbuf + byte);
            const float* bp = bkv + col;
            p += b2f(xv[0]) * bp[0] + b2f(xv[1]) * bp[1] + b2f(xv[2]) * bp[2] + b2f(xv[3]) * bp[3]
               + b2f(xv[4]) * bp[4] + b2f(xv[5]) * bp[5] + b2f(xv[6]) * bp[6] + b2f(xv[7]) * bp[7];
        }
        pl[w][l] = p;
    }
    __syncthreads();
    if (t < 64) c_ws[base + t] = (pl[0][t] + pl[1][t] + pl[2][t] + pl[3][t]) * 0.0625f;

#pragma unroll
    for (int m = 0; m < 4; ++m)
#pragma unroll
        for (int n = 0; n < 4; ++n) acc[m][n] = (f32x4){0.f, 0.f, 0.f, 0.f};
    const short* wkb = Wkvb + (size_t)(w * 64 + lo) * 512 + hi * 8;
#pragma unroll
    for (int ks = 0; ks < 8; ++ks) {
        bf16x8 a[4], b[4];
#pragma unroll
        for (int m = 0; m < 4; ++m) {
            int row = m * 16 + lo;
            int byte = (row << 9) + ks * 64 + hi * 16;
            byte ^= SWZ(row);
            a[m] = *(const bf16x8*)((const char*)cbuf + byte);
        }
#pragma unroll
        for (int n = 0; n < 4; ++n) b[n] = *(const bf16x8*)(wkb + n * 16 * 512 + ks * 32);
#pragma unroll
        for (int m = 0; m < 4; ++m)
#pragma unroll
            for (int n = 0; n < 4; ++n) acc[m][n] = MFMA16(a[m], b[n], acc[m][n]);
    }
#pragma unroll
    for (int m = 0; m < 4; ++m)
#pragma unroll
        for (int n = 0; n < 4; ++n)
#pragma unroll
            for (int j = 0; j < 4; ++j) {
                int s = base + m * 16 + hi * 4 + j;
                int col = w * 64 + n * 16 + lo;
                u_ws[(size_t)s * 256 + col] = acc[m][n][j] * 0.0625f;
            }
}

// ---------------------------------------------------------------------------
// kernel A (8-wave, transposed-MFMA): per 64 objects, 512 threads. [R10 exact]
//  wave w covers h-blocks wh = w*2+mh (mh in [0,2)); acc[mh][nn]: lane holds x
//  for m = nn*16+(l&15), h = wh*16+(l>>4)*4+j.
// LDS: bufIn 16K [0,16K) | x1 32K [16K,48K) | x2 32K [0,32K) after barrier 3.
// 4 barriers. XCD-chunked tile swizzle; vector epilogues; row-split reduce.
// ---------------------------------------------------------------------------
__global__ __launch_bounds__(512, 4) void kA(
        const float* __restrict__ objects, const int* __restrict__ segids,
        const short* __restrict__ W0f, const short* __restrict__ W1f,
        const float* __restrict__ b0, const float* __restrict__ b1,
        const float* __restrict__ u_ws, const float* __restrict__ c_ws,
        float* __restrict__ e_ws, float* __restrict__ Y, float* __restrict__ D) {
    __shared__ char smem[49152];
    __shared__ float pl[8][64];
    __shared__ float e_sh[64];
    __shared__ int sid_sh[64];
    char* bufIn = smem;           // objects bf16 [64][128], dead after GEMM1
    char* x1b   = smem + 16384;   // x1 bf16 [64][256], dead after GEMM2
    char* x2b   = smem;           // x2 bf16 [64][256], written after barrier 3

    const int t = threadIdx.x, w = t >> 6, l = t & 63;
    const int lo = l & 15, hi = l >> 4;
    // T1: XCD-chunked swizzle — each XCD gets a contiguous tile chunk (4096%8==0)
    const int bid = (blockIdx.x & 7) * (gridDim.x >> 3) + (blockIdx.x >> 3);
    const size_t base_row = (size_t)bid * 64;

    if (t < 64) sid_sh[t] = segids[base_row + t];

    // hoist GEMM1 weight A-frags: their L2 latency overlaps the HBM staging below
    bf16x8 w0frag[2][4];  // [mh][ks]
#pragma unroll
    for (int mh = 0; mh < 2; ++mh)
#pragma unroll
        for (int ks = 0; ks < 4; ++ks)
            w0frag[mh][ks] = *(const bf16x8*)(W0f + ((((w * 2 + mh) * 4 + ks) << 9) + (l << 3)));

    // stage objects 64x128 fp32 -> bf16 swizzled (512 threads: 4 iters)
    const float* src = objects + base_row * 128;
#pragma unroll
    for (int i = 0; i < 4; ++i) {
        int fi = (t + i * 512) * 4;
        float4 v = *(const float4*)(src + fi);
        int row = fi >> 7, col = fi & 127;
        int byte = (row << 8) + (col << 1);
        byte ^= SWZ(row);
        uint2 pk;
        pk.x = pack2(v.x, v.y);
        pk.y = pack2(v.z, v.w);
        *(uint2*)(bufIn + byte) = pk;
    }
    __syncthreads();  // barrier 1: bufIn ready

    // GEMM1 (transposed): x1^T = W0^T @ obj^T.  A = hoisted frags, B = bufIn rows.
    f32x4 acc[2][4] = {};
#pragma unroll
    for (int ks = 0; ks < 4; ++ks) {
        bf16x8 bv[4];
#pragma unroll
        for (int nn = 0; nn < 4; ++nn) {
            int m = nn * 16 + lo;
            int byte = (m << 8) + (ks << 6) + (hi << 4);
            byte ^= SWZ(m);
            bv[nn] = *(const bf16x8*)(bufIn + byte);
        }
        __builtin_amdgcn_s_setprio(1);
#pragma unroll
        for (int mh = 0; mh < 2; ++mh)
#pragma unroll
            for (int nn = 0; nn < 4; ++nn) acc[mh][nn] = MFMA16(w0frag[mh][ks], bv[nn], acc[mh][nn]);
        __builtin_amdgcn_s_setprio(0);
    }

    // epilogue 1: x1[m][h] = relu(x + b0) — vector ops, b64 stores
#pragma unroll
    for (int mh = 0; mh < 2; ++mh) {
        const int hcol = (w * 2 + mh) * 16 + hi * 4;
        f32x4 bb = *(const f32x4*)(b0 + hcol);
#pragma unroll
        for (int nn = 0; nn < 4; ++nn) {
            f32x4 v = vmax0(acc[mh][nn] + bb);
            int m = nn * 16 + lo;
            int byte = (m << 9) + (hcol << 1);
            byte ^= SWZ(m);
            uint2 pk;
            pk.x = pack2(v[0], v[1]);
            pk.y = pack2(v[2], v[3]);
            *(uint2*)(x1b + byte) = pk;
        }
    }
    __syncthreads();  // barrier 2: x1 ready

    // GEMM2 (transposed): x2^T = W1^T @ x1^T.  A = W1f frags, B = x1 rows (b128).
#pragma unroll
    for (int mh = 0; mh < 2; ++mh)
#pragma unroll
        for (int nn = 0; nn < 4; ++nn) acc[mh][nn] = (f32x4){0.f, 0.f, 0.f, 0.f};
#pragma unroll
    for (int ks = 0; ks < 8; ++ks) {
        bf16x8 av[2], bv[4];
#pragma unroll
        for (int mh = 0; mh < 2; ++mh)
            av[mh] = *(const bf16x8*)(W1f + ((((w * 2 + mh) * 8 + ks) << 9) + (l << 3)));
#pragma unroll
        for (int nn = 0; nn < 4; ++nn) {
            int m = nn * 16 + lo;
            int byte = (m << 9) + (ks << 6) + (hi << 4);
            byte ^= SWZ(m);
            bv[nn] = *(const bf16x8*)(x1b + byte);
        }
        __builtin_amdgcn_s_setprio(1);
#pragma unroll
        for (int mh = 0; mh < 2; ++mh)
#pragma unroll
            for (int nn = 0; nn < 4; ++nn) acc[mh][nn] = MFMA16(av[mh], bv[nn], acc[mh][nn]);
        __builtin_amdgcn_s_setprio(0);
    }

    // epilogue 2: bias+relu in acc (vector), fused logit partials (vector acc)
    int sids[4];
#pragma unroll
    for (int nn = 0; nn < 4; ++nn) sids[nn] = sid_sh[nn * 16 + lo];
    f32x4 pacc[4] = {};
#pragma unroll
    for (int mh = 0; mh < 2; ++mh) {
        const int hcol = (w * 2 + mh) * 16 + hi * 4;
        f32x4 bb = *(const f32x4*)(b1 + hcol);
#pragma unroll
        for (int nn = 0; nn < 4; ++nn) {
            f32x4 u4 = *(const f32x4*)(u_ws + (size_t)sids[nn] * 256 + hcol);
            f32x4 v = vmax0(acc[mh][nn] + bb);
            acc[mh][nn] = v;
            pacc[nn] += v * u4;
        }
    }
    // cross-hi reduce of logit partials (lanes l, l^16, l^32, l^48)
#pragma unroll
    for (int nn = 0; nn < 4; ++nn) {
        float p = (pacc[nn][0] + pacc[nn][1]) + (pacc[nn][2] + pacc[nn][3]);
        p += __shfl_xor(p, 16);
        p += __shfl_xor(p, 32);
        if (hi == 0) pl[w][nn * 16 + lo] = p;
    }
    __syncthreads();  // barrier 3: x1/bufIn dead; pl published

    // wave 0 computes e and publishes to e_sh (ready at barrier 4)
    if (t < 64) {
        float logit = ((pl[0][t] + pl[1][t]) + (pl[2][t] + pl[3][t]))
                    + ((pl[4][t] + pl[5][t]) + (pl[6][t] + pl[7][t])) + c_ws[sid_sh[t]];
        float e = __expf(logit);  // logits tiny: no max-subtraction needed
        e_sh[t] = e;
        e_ws[base_row + t] = e;
    }

    // store x2 (overlays bufIn + x1 low half)
#pragma unroll
    for (int mh = 0; mh < 2; ++mh) {
        const int hcol = (w * 2 + mh) * 16 + hi * 4;
#pragma unroll
        for (int nn = 0; nn < 4; ++nn) {
            int m = nn * 16 + lo;
            int byte = (m << 9) + (hcol << 1);
            byte ^= SWZ(m);
            uint2 pk;
            pk.x = pack2(acc[mh][nn][0], acc[mh][nn][1]);
            pk.y = pack2(acc[mh][nn][2], acc[mh][nn][3]);
            *(uint2*)(x2b + byte) = pk;
        }
    }
    __syncthreads();  // barrier 4: x2 + e_sh ready

    // Y/D reduce: row-split across thread halves (col = t&255, rows half*32..+31);
    // statically unrolled; flush at run boundaries or half-end (partial sums
    // merge via atomics). || short-circuit guards sid_sh[64] OOB.
    {
        const int col = t & 255;
        const int hbase = (t >> 8) * 32;
        const int hend = hbase + 31;
        float ysum = 0.f, dsum = 0.f;
#pragma unroll
        for (int rr = 0; rr < 32; ++rr) {
            const int r = hbase + rr;
            float er = e_sh[r];
            int byte = ((r << 9) + (col << 1)) ^ SWZ(r);
            ysum += er * b2f(*(const short*)(x2b + byte));
            dsum += er;
            if ((r == hend) || (sid_sh[r + 1] != sid_sh[r])) {  // uniform flush
                int s = sid_sh[r];
                atomicAdd(Y + (size_t)s * 256 + col, ysum);
                if (col == 0) atomicAdd(D + s, dsum);
                ysum = 0.f;
                dsum = 0.f;
            }
        }
    }
}

// ---------------------------------------------------------------------------
// kEmbW: 16 segments/block: emb_s = (Y_s/den) @ Wv + (den/max(den,eps))*bv
//        + fused w_i = e_i / max(D[sid_i], eps) (grid-stride tail)
// ---------------------------------------------------------------------------
__global__ __launch_bounds__(256) void kEmbW(const float* __restrict__ Y,
                                             const float* __restrict__ D,
                                             const float* __restrict__ Wkv,
                                             const float* __restrict__ bkv,
                                             const float* __restrict__ e,
                                             const int* __restrict__ segids,
                                             float* __restrict__ emb,
                                             float* __restrict__ wout, int nobj) {
    __shared__ float ysh[16][256];
    __shared__ float sw[16];
    const int t = threadIdx.x;
    const int s0 = blockIdx.x * 16;
#pragma unroll
    for (int i = 0; i < 16; ++i) {
        float d = D[s0 + i];
        float dm = fmaxf(d, 1e-9f);
        ysh[i][t] = Y[(size_t)(s0 + i) * 256 + t] / dm;
        if (t == 0) sw[i] = d / dm;
    }
    __syncthreads();
    float acc[16] = {};
    for (int h = 0; h < 256; ++h) {
        float wv = Wkv[(size_t)h * 512 + 256 + t];  // fp32 V weights (accuracy)
#pragma unroll
        for (int i = 0; i < 16; ++i) acc[i] += ysh[i][h] * wv;
    }
    float bv = bkv[256 + t];
#pragma unroll
    for (int i = 0; i < 16; ++i) emb[(size_t)(s0 + i) * 256 + t] = acc[i] + sw[i] * bv;

    // fused w output
    for (int i = blockIdx.x * 256 + t; i < nobj; i += gridDim.x * 256)
        wout[i] = e[i] / fmaxf(D[segids[i]], 1e-9f);
}

// ---------------------------------------------------------------------------
extern "C" void kernel_launch(void* const* d_in, const int* in_sizes, int n_in,
                              void* d_out, int out_size, void* d_ws, size_t ws_size,
                              hipStream_t stream) {
    const float* objects = (const float*)d_in[0];
    const float* context = (const float*)d_in[1];
    const int* segids    = (const int*)d_in[2];
    const float* W0  = (const float*)d_in[4];
    const float* b0  = (const float*)d_in[5];
    const float* W1  = (const float*)d_in[6];
    const float* b1  = (const float*)d_in[7];
    const float* Wkv = (const float*)d_in[8];
    const float* bkv = (const float*)d_in[9];
    const float* Wq  = (const float*)d_in[10];
    const float* bq  = (const float*)d_in[11];

    const int NT = in_sizes[2];        // 262144
    const int B  = in_sizes[1] / 256;  // 4096

    char* wsb = (char*)d_ws;
    short* W0f  = (short*)(wsb + 0);        // 64 KB
    short* W1f  = (short*)(wsb + 65536);    // 128 KB
    short* Wkvb = (short*)(wsb + 196608);   // 256 KB
    short* Wqt  = (short*)(wsb + 458752);   // 128 KB
    float* u_ws = (float*)(wsb + 589824);   // 4 MB
    float* c_ws = (float*)(wsb + 4784128);  // 16 KB
    float* e_ws = (float*)(wsb + 4800512);  // 1 MB
    float* Y    = (float*)(wsb + 5849088);  // 4 MB
    float* D    = (float*)(wsb + 10043392); // 16 KB

    float* emb_out = (float*)d_out;
    float* w_out   = (float*)d_out + (size_t)B * 256;

    kPrep0<<<512, 256, 0, stream>>>(W0, W1, Wkv, Wq, W0f, W1f, Wkvb, Wqt, Y, D);
    kPrep1<<<B / 64, 256, 0, stream>>>(context, Wqt, bq, Wkvb, bkv, u_ws, c_ws);
    kA<<<NT / 64, 512, 0, stream>>>(objects, segids, W0f, W1f, b0, b1, u_ws, c_ws, e_ws, Y, D);
    kEmbW<<<B / 16, 256, 0, stream>>>(Y, D, Wkv, bkv, e_ws, segids, emb_out, w_out, NT);
}

// Round 15
// 137.381 us; speedup vs baseline: 1.2076x; 1.0366x over previous
//
#include <hip/hip_runtime.h>
#include <hip/hip_bf16.h>

// ObjectSelector: fused MLP -> segment softmax -> segment-weighted embedding.
// Algebra: logit_i = x2_i . u_{s_i} + c_{s_i}   (u_s = Wk @ q_s, c_s = bk.q_s, /16 folded in)
//          emb_s   = (sum_i e_i x2_i)/den @ Wv + bv     (linearity of V-projection)
// kA computes GEMM1/GEMM2 TRANSPOSED (x^T = W^T @ obj^T).
// R15 = R10 frozen (kA verified best: 64-row tiles, 8 waves, bounds(512,4),
// VGPR 44, ~112us; memset; kEmbW 8-seg) + kPrep1 re-tiled to M=32 (128 blocks,
// 2x CU coverage — it was 64 blocks on 256 CUs).
// Ledger: R5 resident-tile thrash; R7/R11 spill = WRITE balloon; R9/R13
// compiler folds flat hoists; R11/R12 bigger tiles lose occupancy.

typedef __attribute__((ext_vector_type(8))) short bf16x8;
typedef __attribute__((ext_vector_type(4))) float f32x4;
typedef __attribute__((ext_vector_type(4))) short s16x4;

__device__ __forceinline__ float b2f(short s) {
    unsigned int u = ((unsigned int)(unsigned short)s) << 16;
    float f;
    __builtin_memcpy(&f, &u, 4);
    return f;
}
__device__ __forceinline__ short f2b(float x) {
    __hip_bfloat16 h = __float2bfloat16(x);
    short s;
    __builtin_memcpy(&s, &h, 2);
    return s;
}
__device__ __forceinline__ unsigned pack2(float a, float b) {
    return ((unsigned)(unsigned short)f2b(a)) | (((unsigned)(unsigned short)f2b(b)) << 16);
}
__device__ __forceinline__ f32x4 vmax0(f32x4 v) {
    f32x4 r;
    r[0] = fmaxf(v[0], 0.f); r[1] = fmaxf(v[1], 0.f);
    r[2] = fmaxf(v[2], 0.f); r[3] = fmaxf(v[3], 0.f);
    return r;
}

#define MFMA16(a, b, c) __builtin_amdgcn_mfma_f32_16x16x32_bf16(a, b, c, 0, 0, 0)
#define SWZ(row) (((row) & 7) << 4)   // XOR-swizzle on 16B chunks (G4 bank-conflict fix)

// ---------------------------------------------------------------------------
// prep0: weights -> bf16.
//  W0f: frag-ordered W0^T: i = ((wh*4+ks)*64+lane)*8+e,  wh in [0,16)
//       value = W0[k][h], h=wh*16+(lane&15), k=ks*32+(lane>>4)*8+e
//  W1f: frag-ordered W1^T: i = ((wh*8+ks)*64+lane)*8+e  (same mapping, K=256)
//  Wqt[n][k] (256x256), Wkvb straight copy (256x512)   (for kPrep1)
// ---------------------------------------------------------------------------
__global__ void kPrep0(const float* __restrict__ W0, const float* __restrict__ W1,
                       const float* __restrict__ Wkv, const float* __restrict__ Wq,
                       short* __restrict__ W0f, short* __restrict__ W1f,
                       short* __restrict__ Wkvb, short* __restrict__ Wqt) {
    int i = blockIdx.x * 256 + threadIdx.x;  // grid covers 131072
    if (i < 32768) {
        int e = i & 7, lane = (i >> 3) & 63, ks = (i >> 9) & 3, wh = (i >> 11) & 15;
        int h = wh * 16 + (lane & 15);
        int k = ks * 32 + (lane >> 4) * 8 + e;
        W0f[i] = f2b(W0[k * 256 + h]);
    }
    if (i < 65536) {
        int e = i & 7, lane = (i >> 3) & 63, ks = (i >> 9) & 7, wh = (i >> 12) & 15;
        int h = wh * 16 + (lane & 15);
        int k = ks * 32 + (lane >> 4) * 8 + e;
        W1f[i] = f2b(W1[k * 256 + h]);
        int n = i >> 8, kk = i & 255;
        Wqt[i] = f2b(Wq[kk * 256 + n]);
    }
    if (i < 131072) Wkvb[i] = f2b(Wkv[i]);
}

// ---------------------------------------------------------------------------
// prep1 (M=32 tiles, 128 blocks): per 32 context rows:
//   q = ctx@Wq + bq; c = (q.bk)/16; u = (q@Wk^T)/16
// c-partials: lanes <32 cover j 0..3, lanes >=32 cover j 4..7 of the wave's
// 64-col slice (row = l&31); c_ws sums both halves.
// ---------------------------------------------------------------------------
__global__ __launch_bounds__(256) void kPrep1(
        const float* __restrict__ context, const short* __restrict__ Wqt,
        const float* __restrict__ bq, const short* __restrict__ Wkvb,
        const float* __restrict__ bkv, float* __restrict__ u_ws,
        float* __restrict__ c_ws) {
    __shared__ short cbuf[32 * 256];
    __shared__ float pl[4][64];
    const int t = threadIdx.x, w = t >> 6, l = t & 63;
    const int lo = l & 15, hi = l >> 4;
    const int base = blockIdx.x * 32;

    const float* src = context + (size_t)base * 256;
#pragma unroll
    for (int i = 0; i < 8; ++i) {
        int fi = (t + i * 256) * 4;
        float4 v = *(const float4*)(src + fi);
        int row = fi >> 8, col = fi & 255;
        int byte = (row << 9) + (col << 1);
        byte ^= SWZ(row);
        s16x4 pk;
        pk[0] = f2b(v.x); pk[1] = f2b(v.y); pk[2] = f2b(v.z); pk[3] = f2b(v.w);
        *(s16x4*)((char*)cbuf + byte) = pk;
    }
    __syncthreads();

    // GEMM: q = ctx @ Wqt  (M=32 -> m<2, N=256 split 4 waves, K=256)
    f32x4 acc[2][4] = {};
    const short* wqb = Wqt + (size_t)(w * 64 + lo) * 256 + hi * 8;
#pragma unroll
    for (int ks = 0; ks < 8; ++ks) {
        bf16x8 a[2], b[4];
#pragma unroll
        for (int m = 0; m < 2; ++m) {
            int row = m * 16 + lo;
            int byte = (row << 9) + ks * 64 + hi * 16;
            byte ^= SWZ(row);
            a[m] = *(const bf16x8*)((const char*)cbuf + byte);
        }
#pragma unroll
        for (int n = 0; n < 4; ++n) b[n] = *(const bf16x8*)(wqb + n * 16 * 256 + ks * 32);
#pragma unroll
        for (int m = 0; m < 2; ++m)
#pragma unroll
            for (int n = 0; n < 4; ++n) acc[m][n] = MFMA16(a[m], b[n], acc[m][n]);
    }
    __syncthreads();

    float bqv[4];
#pragma unroll
    for (int n = 0; n < 4; ++n) bqv[n] = bq[w * 64 + n * 16 + lo];
#pragma unroll
    for (int m = 0; m < 2; ++m)
#pragma unroll
        for (int n = 0; n < 4; ++n)
#pragma unroll
            for (int j = 0; j < 4; ++j) {
                float q = acc[m][n][j] + bqv[n];
                int row = m * 16 + hi * 4 + j;
                int col = w * 64 + n * 16 + lo;
                int byte = (row << 9) + (col << 1);
                byte ^= SWZ(row);
                *(short*)((char*)cbuf + byte) = f2b(q);
            }
    __syncthreads();

    // c partials: row = l&31, j-half by lane half
    {
        const int row = l & 31;
        const int jbase = (l >> 5) * 4;
        float p = 0.f;
#pragma unroll
        for (int j = 0; j < 4; ++j) {
            int col = w * 64 + (jbase + j) * 8;
            int byte = (row << 9) + (col << 1);
            byte ^= SWZ(row);
            bf16x8 xv = *(const bf16x8*)((const char*)cbuf + byte);
            const float* bp = bkv + col;
            p += b2f(xv[0]) * bp[0] + b2f(xv[1]) * bp[1] + b2f(xv[2]) * bp[2] + b2f(xv[3]) * bp[3]
               + b2f(xv[4]) * bp[4] + b2f(xv[5]) * bp[5] + b2f(xv[6]) * bp[6] + b2f(xv[7]) * bp[7];
        }
        pl[w][l] = p;
    }
    __syncthreads();
    if (t < 32)
        c_ws[base + t] = ((pl[0][t] + pl[0][t + 32]) + (pl[1][t] + pl[1][t + 32])
                        + (pl[2][t] + pl[2][t + 32]) + (pl[3][t] + pl[3][t + 32])) * 0.0625f;

    // u = q @ Wk^T
#pragma unroll
    for (int m = 0; m < 2; ++m)
#pragma unroll
        for (int n = 0; n < 4; ++n) acc[m][n] = (f32x4){0.f, 0.f, 0.f, 0.f};
    const short* wkb = Wkvb + (size_t)(w * 64 + lo) * 512 + hi * 8;
#pragma unroll
    for (int ks = 0; ks < 8; ++ks) {
        bf16x8 a[2], b[4];
#pragma unroll
        for (int m = 0; m < 2; ++m) {
            int row = m * 16 + lo;
            int byte = (row << 9) + ks * 64 + hi * 16;
            byte ^= SWZ(row);
            a[m] = *(const bf16x8*)((const char*)cbuf + byte);
        }
#pragma unroll
        for (int n = 0; n < 4; ++n) b[n] = *(const bf16x8*)(wkb + n * 16 * 512 + ks * 32);
#pragma unroll
        for (int m = 0; m < 2; ++m)
#pragma unroll
            for (int n = 0; n < 4; ++n) acc[m][n] = MFMA16(a[m], b[n], acc[m][n]);
    }
#pragma unroll
    for (int m = 0; m < 2; ++m)
#pragma unroll
        for (int n = 0; n < 4; ++n)
#pragma unroll
            for (int j = 0; j < 4; ++j) {
                int s = base + m * 16 + hi * 4 + j;
                int col = w * 64 + n * 16 + lo;
                u_ws[(size_t)s * 256 + col] = acc[m][n][j] * 0.0625f;
            }
}

// ---------------------------------------------------------------------------
// kernel A (8-wave, transposed-MFMA): per 64 objects, 512 threads. [R10 exact]
//  wave w covers h-blocks wh = w*2+mh (mh in [0,2)); acc[mh][nn]: lane holds x
//  for m = nn*16+(l&15), h = wh*16+(l>>4)*4+j.
// LDS: bufIn 16K [0,16K) | x1 32K [16K,48K) | x2 32K [0,32K) after barrier 3.
// 4 barriers. XCD-chunked tile swizzle; vector epilogues; row-split reduce.
// ---------------------------------------------------------------------------
__global__ __launch_bounds__(512, 4) void kA(
        const float* __restrict__ objects, const int* __restrict__ segids,
        const short* __restrict__ W0f, const short* __restrict__ W1f,
        const float* __restrict__ b0, const float* __restrict__ b1,
        const float* __restrict__ u_ws, const float* __restrict__ c_ws,
        float* __restrict__ e_ws, float* __restrict__ Y, float* __restrict__ D) {
    __shared__ char smem[49152];
    __shared__ float pl[8][64];
    __shared__ float e_sh[64];
    __shared__ int sid_sh[64];
    char* bufIn = smem;           // objects bf16 [64][128], dead after GEMM1
    char* x1b   = smem + 16384;   // x1 bf16 [64][256], dead after GEMM2
    char* x2b   = smem;           // x2 bf16 [64][256], written after barrier 3

    const int t = threadIdx.x, w = t >> 6, l = t & 63;
    const int lo = l & 15, hi = l >> 4;
    // T1: XCD-chunked swizzle — each XCD gets a contiguous tile chunk (4096%8==0)
    const int bid = (blockIdx.x & 7) * (gridDim.x >> 3) + (blockIdx.x >> 3);
    const size_t base_row = (size_t)bid * 64;

    if (t < 64) sid_sh[t] = segids[base_row + t];

    // hoist GEMM1 weight A-frags: their L2 latency overlaps the HBM staging below
    bf16x8 w0frag[2][4];  // [mh][ks]
#pragma unroll
    for (int mh = 0; mh < 2; ++mh)
#pragma unroll
        for (int ks = 0; ks < 4; ++ks)
            w0frag[mh][ks] = *(const bf16x8*)(W0f + ((((w * 2 + mh) * 4 + ks) << 9) + (l << 3)));

    // stage objects 64x128 fp32 -> bf16 swizzled (512 threads: 4 iters)
    const float* src = objects + base_row * 128;
#pragma unroll
    for (int i = 0; i < 4; ++i) {
        int fi = (t + i * 512) * 4;
        float4 v = *(const float4*)(src + fi);
        int row = fi >> 7, col = fi & 127;
        int byte = (row << 8) + (col << 1);
        byte ^= SWZ(row);
        uint2 pk;
        pk.x = pack2(v.x, v.y);
        pk.y = pack2(v.z, v.w);
        *(uint2*)(bufIn + byte) = pk;
    }
    __syncthreads();  // barrier 1: bufIn ready

    // GEMM1 (transposed): x1^T = W0^T @ obj^T.  A = hoisted frags, B = bufIn rows.
    f32x4 acc[2][4] = {};
#pragma unroll
    for (int ks = 0; ks < 4; ++ks) {
        bf16x8 bv[4];
#pragma unroll
        for (int nn = 0; nn < 4; ++nn) {
            int m = nn * 16 + lo;
            int byte = (m << 8) + (ks << 6) + (hi << 4);
            byte ^= SWZ(m);
            bv[nn] = *(const bf16x8*)(bufIn + byte);
        }
        __builtin_amdgcn_s_setprio(1);
#pragma unroll
        for (int mh = 0; mh < 2; ++mh)
#pragma unroll
            for (int nn = 0; nn < 4; ++nn) acc[mh][nn] = MFMA16(w0frag[mh][ks], bv[nn], acc[mh][nn]);
        __builtin_amdgcn_s_setprio(0);
    }

    // epilogue 1: x1[m][h] = relu(x + b0) — vector ops, b64 stores
#pragma unroll
    for (int mh = 0; mh < 2; ++mh) {
        const int hcol = (w * 2 + mh) * 16 + hi * 4;
        f32x4 bb = *(const f32x4*)(b0 + hcol);
#pragma unroll
        for (int nn = 0; nn < 4; ++nn) {
            f32x4 v = vmax0(acc[mh][nn] + bb);
            int m = nn * 16 + lo;
            int byte = (m << 9) + (hcol << 1);
            byte ^= SWZ(m);
            uint2 pk;
            pk.x = pack2(v[0], v[1]);
            pk.y = pack2(v[2], v[3]);
            *(uint2*)(x1b + byte) = pk;
        }
    }
    __syncthreads();  // barrier 2: x1 ready

    // GEMM2 (transposed): x2^T = W1^T @ x1^T.  A = W1f frags, B = x1 rows (b128).
#pragma unroll
    for (int mh = 0; mh < 2; ++mh)
#pragma unroll
        for (int nn = 0; nn < 4; ++nn) acc[mh][nn] = (f32x4){0.f, 0.f, 0.f, 0.f};
#pragma unroll
    for (int ks = 0; ks < 8; ++ks) {
        bf16x8 av[2], bv[4];
#pragma unroll
        for (int mh = 0; mh < 2; ++mh)
            av[mh] = *(const bf16x8*)(W1f + ((((w * 2 + mh) * 8 + ks) << 9) + (l << 3)));
#pragma unroll
        for (int nn = 0; nn < 4; ++nn) {
            int m = nn * 16 + lo;
            int byte = (m << 9) + (ks << 6) + (hi << 4);
            byte ^= SWZ(m);
            bv[nn] = *(const bf16x8*)(x1b + byte);
        }
        __builtin_amdgcn_s_setprio(1);
#pragma unroll
        for (int mh = 0; mh < 2; ++mh)
#pragma unroll
            for (int nn = 0; nn < 4; ++nn) acc[mh][nn] = MFMA16(av[mh], bv[nn], acc[mh][nn]);
        __builtin_amdgcn_s_setprio(0);
    }

    // epilogue 2: bias+relu in acc (vector), fused logit partials (vector acc)
    int sids[4];
#pragma unroll
    for (int nn = 0; nn < 4; ++nn) sids[nn] = sid_sh[nn * 16 + lo];
    f32x4 pacc[4] = {};
#pragma unroll
    for (int mh = 0; mh < 2; ++mh) {
        const int hcol = (w * 2 + mh) * 16 + hi * 4;
        f32x4 bb = *(const f32x4*)(b1 + hcol);
#pragma unroll
        for (int nn = 0; nn < 4; ++nn) {
            f32x4 u4 = *(const f32x4*)(u_ws + (size_t)sids[nn] * 256 + hcol);
            f32x4 v = vmax0(acc[mh][nn] + bb);
            acc[mh][nn] = v;
            pacc[nn] += v * u4;
        }
    }
    // cross-hi reduce of logit partials (lanes l, l^16, l^32, l^48)
#pragma unroll
    for (int nn = 0; nn < 4; ++nn) {
        float p = (pacc[nn][0] + pacc[nn][1]) + (pacc[nn][2] + pacc[nn][3]);
        p += __shfl_xor(p, 16);
        p += __shfl_xor(p, 32);
        if (hi == 0) pl[w][nn * 16 + lo] = p;
    }
    __syncthreads();  // barrier 3: x1/bufIn dead; pl published

    // wave 0 computes e and publishes to e_sh (ready at barrier 4)
    if (t < 64) {
        float logit = ((pl[0][t] + pl[1][t]) + (pl[2][t] + pl[3][t]))
                    + ((pl[4][t] + pl[5][t]) + (pl[6][t] + pl[7][t])) + c_ws[sid_sh[t]];
        float e = __expf(logit);  // logits tiny: no max-subtraction needed
        e_sh[t] = e;
        e_ws[base_row + t] = e;
    }

    // store x2 (overlays bufIn + x1 low half)
#pragma unroll
    for (int mh = 0; mh < 2; ++mh) {
        const int hcol = (w * 2 + mh) * 16 + hi * 4;
#pragma unroll
        for (int nn = 0; nn < 4; ++nn) {
            int m = nn * 16 + lo;
            int byte = (m << 9) + (hcol << 1);
            byte ^= SWZ(m);
            uint2 pk;
            pk.x = pack2(acc[mh][nn][0], acc[mh][nn][1]);
            pk.y = pack2(acc[mh][nn][2], acc[mh][nn][3]);
            *(uint2*)(x2b + byte) = pk;
        }
    }
    __syncthreads();  // barrier 4: x2 + e_sh ready

    // Y/D reduce: row-split across thread halves (col = t&255, rows half*32..+31);
    // statically unrolled; flush at run boundaries or half-end (partial sums
    // merge via atomics). || short-circuit guards sid_sh[64] OOB.
    {
        const int col = t & 255;
        const int hbase = (t >> 8) * 32;
        const int hend = hbase + 31;
        float ysum = 0.f, dsum = 0.f;
#pragma unroll
        for (int rr = 0; rr < 32; ++rr) {
            const int r = hbase + rr;
            float er = e_sh[r];
            int byte = ((r << 9) + (col << 1)) ^ SWZ(r);
            ysum += er * b2f(*(const short*)(x2b + byte));
            dsum += er;
            if ((r == hend) || (sid_sh[r + 1] != sid_sh[r])) {  // uniform flush
                int s = sid_sh[r];
                atomicAdd(Y + (size_t)s * 256 + col, ysum);
                if (col == 0) atomicAdd(D + s, dsum);
                ysum = 0.f;
                dsum = 0.f;
            }
        }
    }
}

// ---------------------------------------------------------------------------
// kEmbW: 8 segments/block: emb_s = (Y_s/den) @ Wv + (den/max(den,eps))*bv
//        + fused w_i = e_i / max(D[sid_i], eps) (grid-stride tail)
// ---------------------------------------------------------------------------
__global__ __launch_bounds__(256) void kEmbW(const float* __restrict__ Y,
                                             const float* __restrict__ D,
                                             const float* __restrict__ Wkv,
                                             const float* __restrict__ bkv,
                                             const float* __restrict__ e,
                                             const int* __restrict__ segids,
                                             float* __restrict__ emb,
                                             float* __restrict__ wout, int nobj) {
    __shared__ float ysh[8][256];
    __shared__ float sw[8];
    const int t = threadIdx.x;
    const int s0 = blockIdx.x * 8;
#pragma unroll
    for (int i = 0; i < 8; ++i) {
        float d = D[s0 + i];
        float dm = fmaxf(d, 1e-9f);
        ysh[i][t] = Y[(size_t)(s0 + i) * 256 + t] / dm;
        if (t == 0) sw[i] = d / dm;
    }
    __syncthreads();
    float acc[8] = {0.f, 0.f, 0.f, 0.f, 0.f, 0.f, 0.f, 0.f};
    for (int h = 0; h < 256; ++h) {
        float wv = Wkv[(size_t)h * 512 + 256 + t];  // fp32 V weights (accuracy)
#pragma unroll
        for (int i = 0; i < 8; ++i) acc[i] += ysh[i][h] * wv;
    }
    float bv = bkv[256 + t];
#pragma unroll
    for (int i = 0; i < 8; ++i) emb[(size_t)(s0 + i) * 256 + t] = acc[i] + sw[i] * bv;

    // fused w output
    for (int i = blockIdx.x * 256 + t; i < nobj; i += gridDim.x * 256)
        wout[i] = e[i] / fmaxf(D[segids[i]], 1e-9f);
}

// ---------------------------------------------------------------------------
extern "C" void kernel_launch(void* const* d_in, const int* in_sizes, int n_in,
                              void* d_out, int out_size, void* d_ws, size_t ws_size,
                              hipStream_t stream) {
    const float* objects = (const float*)d_in[0];
    const float* context = (const float*)d_in[1];
    const int* segids    = (const int*)d_in[2];
    const float* W0  = (const float*)d_in[4];
    const float* b0  = (const float*)d_in[5];
    const float* W1  = (const float*)d_in[6];
    const float* b1  = (const float*)d_in[7];
    const float* Wkv = (const float*)d_in[8];
    const float* bkv = (const float*)d_in[9];
    const float* Wq  = (const float*)d_in[10];
    const float* bq  = (const float*)d_in[11];

    const int NT = in_sizes[2];        // 262144
    const int B  = in_sizes[1] / 256;  // 4096

    char* wsb = (char*)d_ws;
    short* W0f  = (short*)(wsb + 0);        // 64 KB
    short* W1f  = (short*)(wsb + 65536);    // 128 KB
    short* Wkvb = (short*)(wsb + 196608);   // 256 KB
    short* Wqt  = (short*)(wsb + 458752);   // 128 KB
    float* u_ws = (float*)(wsb + 589824);   // 4 MB
    float* c_ws = (float*)(wsb + 4784128);  // 16 KB
    float* e_ws = (float*)(wsb + 4800512);  // 1 MB
    float* Y    = (float*)(wsb + 5849088);  // 4 MB
    float* D    = (float*)(wsb + 10043392); // 16 KB

    float* emb_out = (float*)d_out;
    float* w_out   = (float*)d_out + (size_t)B * 256;

    hipMemsetAsync(wsb + 5849088, 0, 4194304 + 16384, stream);  // zero Y, D
    kPrep0<<<512, 256, 0, stream>>>(W0, W1, Wkv, Wq, W0f, W1f, Wkvb, Wqt);
    kPrep1<<<B / 32, 256, 0, stream>>>(context, Wqt, bq, Wkvb, bkv, u_ws, c_ws);
    kA<<<NT / 64, 512, 0, stream>>>(objects, segids, W0f, W1f, b0, b1, u_ws, c_ws, e_ws, Y, D);
    kEmbW<<<B / 8, 256, 0, stream>>>(Y, D, Wkv, bkv, e_ws, segids, emb_out, w_out, NT);
}